// Round 1
// baseline (2244.100 us; speedup 1.0000x reference)
//
#include <hip/hip_runtime.h>

#define N_NODES 50000
#define N_EDGES 600000
#define D 128
#define K3 (3 * D)
#define TN 64
#define BK 16

// ---------------- degree ----------------
__global__ __launch_bounds__(256) void degree_kernel(const int* __restrict__ dst,
                                                     float* __restrict__ deg) {
    int e = blockIdx.x * blockDim.x + threadIdx.x;
    if (e < N_EDGES) atomicAdd(&deg[dst[e]], 1.0f);
}

__global__ __launch_bounds__(256) void invdeg_kernel(float* __restrict__ deg) {
    int i = blockIdx.x * blockDim.x + threadIdx.x;
    if (i < N_NODES) deg[i] = 1.0f / fmaxf(deg[i], 1.0f);
}

// ---------------- scatter-add: sum[dst] += xin[src] ----------------
// 32 threads per edge, one float4 per thread (coalesced gather of the src row).
__global__ __launch_bounds__(256) void scatter_kernel(const float* __restrict__ xin,
                                                      const int* __restrict__ src,
                                                      const int* __restrict__ dst,
                                                      float* __restrict__ sum) {
    unsigned t = blockIdx.x * blockDim.x + threadIdx.x;
    unsigned e = t >> 5;
    if (e >= N_EDGES) return;
    unsigned d4 = (t & 31u) << 2;
    int s = src[e];
    int dd = dst[e];
    float4 v = *(const float4*)(xin + (size_t)s * D + d4);
    float* o = sum + (size_t)dd * D + d4;
    atomicAdd(o + 0, v.x);
    atomicAdd(o + 1, v.y);
    atomicAdd(o + 2, v.z);
    atomicAdd(o + 3, v.w);
}

// ---------------- in-place scale by invdeg ----------------
__global__ __launch_bounds__(256) void scale_kernel(float* __restrict__ buf,
                                                    const float* __restrict__ invdeg) {
    unsigned t = blockIdx.x * blockDim.x + threadIdx.x;
    if (t >= (unsigned)N_NODES * (D / 4)) return;
    unsigned n = t >> 5;  // D/4 == 32 quads per node
    float s = invdeg[n];
    float4* p = (float4*)buf + t;
    float4 v = *p;
    v.x *= s; v.y *= s; v.z *= s; v.w *= s;
    *p = v;
}

// ---------------- fp32 GEMM: out[N,128] = concat(x,h1,h2) @ W^T + b ----------------
// 256 threads/block, 64 nodes x 128 outputs per block, BK=16, 4x8 micro-tile.
__global__ __launch_bounds__(256) void gemm_kernel(const float* __restrict__ x,
                                                   const float* __restrict__ h1,
                                                   const float* __restrict__ h2,
                                                   const float* __restrict__ W,
                                                   const float* __restrict__ bias,
                                                   float* __restrict__ out) {
    __shared__ float fT[BK][TN + 4];  // feats tile transposed: [k][n]
    __shared__ float wT[BK][D];       // W tile transposed:     [k][o]
    const int tid = threadIdx.x;
    const int base = blockIdx.x * TN;
    const int tx = tid & 15;  // output group: outputs tx*8 .. tx*8+7
    const int ty = tid >> 4;  // node group:   nodes   ty*4 .. ty*4+3

    float acc[4][8];
#pragma unroll
    for (int j = 0; j < 4; ++j)
#pragma unroll
        for (int i = 0; i < 8; ++i) acc[j][i] = 0.0f;

    // staging mapping: feats — 4 threads per row, float4 each
    const int sr = tid >> 2;           // row 0..63
    const int skq = (tid & 3) << 2;    // k offset 0,4,8,12
    int srow = base + sr;
    if (srow >= N_NODES) srow = N_NODES - 1;  // clamp; stores are guarded

    // W staging: 512 float4 segments, 2 per thread
    const int o1 = tid >> 2;
    const int o2 = (tid + 256) >> 2;
    const int kq1 = (tid & 3) << 2;  // same for both iterations

    const float* segs[3] = {x, h1, h2};

    for (int k0 = 0; k0 < K3; k0 += BK) {
        const float* seg = segs[k0 >> 7];
        const int kl = k0 & (D - 1);
        float4 fv = *(const float4*)(seg + (size_t)srow * D + kl + skq);
        float4 wv1 = *(const float4*)(W + (size_t)o1 * K3 + k0 + kq1);
        float4 wv2 = *(const float4*)(W + (size_t)o2 * K3 + k0 + kq1);
        __syncthreads();  // previous iteration's LDS reads complete
        fT[skq + 0][sr] = fv.x;
        fT[skq + 1][sr] = fv.y;
        fT[skq + 2][sr] = fv.z;
        fT[skq + 3][sr] = fv.w;
        wT[kq1 + 0][o1] = wv1.x;
        wT[kq1 + 1][o1] = wv1.y;
        wT[kq1 + 2][o1] = wv1.z;
        wT[kq1 + 3][o1] = wv1.w;
        wT[kq1 + 0][o2] = wv2.x;
        wT[kq1 + 1][o2] = wv2.y;
        wT[kq1 + 2][o2] = wv2.z;
        wT[kq1 + 3][o2] = wv2.w;
        __syncthreads();
#pragma unroll
        for (int kk = 0; kk < BK; ++kk) {
            float4 a4 = *(const float4*)&fT[kk][ty << 2];
            float4 w0 = *(const float4*)&wT[kk][tx << 3];
            float4 w1 = *(const float4*)&wT[kk][(tx << 3) + 4];
            const float a[4] = {a4.x, a4.y, a4.z, a4.w};
            const float w[8] = {w0.x, w0.y, w0.z, w0.w, w1.x, w1.y, w1.z, w1.w};
#pragma unroll
            for (int j = 0; j < 4; ++j)
#pragma unroll
                for (int i = 0; i < 8; ++i)
                    acc[j][i] = fmaf(a[j], w[i], acc[j][i]);
        }
    }

    float bv[8];
#pragma unroll
    for (int i = 0; i < 8; ++i) bv[i] = bias[(tx << 3) + i];
#pragma unroll
    for (int j = 0; j < 4; ++j) {
        int n = base + (ty << 2) + j;
        if (n < N_NODES) {
            float4 q0 = make_float4(acc[j][0] + bv[0], acc[j][1] + bv[1],
                                    acc[j][2] + bv[2], acc[j][3] + bv[3]);
            float4 q1 = make_float4(acc[j][4] + bv[4], acc[j][5] + bv[5],
                                    acc[j][6] + bv[6], acc[j][7] + bv[7]);
            *(float4*)(out + (size_t)n * D + (tx << 3)) = q0;
            *(float4*)(out + (size_t)n * D + (tx << 3) + 4) = q1;
        }
    }
}

extern "C" void kernel_launch(void* const* d_in, const int* in_sizes, int n_in,
                              void* d_out, int out_size, void* d_ws, size_t ws_size,
                              hipStream_t stream) {
    const float* x = (const float*)d_in[0];
    const int* ei = (const int*)d_in[1];
    const float* W = (const float*)d_in[2];
    const float* b = (const float*)d_in[3];
    float* out = (float*)d_out;
    const int* src = ei;            // edge_index[0,:]
    const int* dst = ei + N_EDGES;  // edge_index[1,:]

    // workspace: h1 [N*D] f32 | h2 [N*D] f32 | deg [N] f32  (~51.4 MB)
    float* h1 = (float*)d_ws;
    float* h2 = h1 + (size_t)N_NODES * D;
    float* deg = h2 + (size_t)N_NODES * D;

    hipMemsetAsync(h1, 0, (size_t)N_NODES * D * sizeof(float), stream);
    hipMemsetAsync(h2, 0, (size_t)N_NODES * D * sizeof(float), stream);
    hipMemsetAsync(deg, 0, (size_t)N_NODES * sizeof(float), stream);

    degree_kernel<<<(N_EDGES + 255) / 256, 256, 0, stream>>>(dst, deg);
    invdeg_kernel<<<(N_NODES + 255) / 256, 256, 0, stream>>>(deg);

    const int sgrid = (N_EDGES * 32 + 255) / 256;
    const int cgrid = (N_NODES * 32 + 255) / 256;

    scatter_kernel<<<sgrid, 256, 0, stream>>>(x, src, dst, h1);
    scale_kernel<<<cgrid, 256, 0, stream>>>(h1, deg);

    scatter_kernel<<<sgrid, 256, 0, stream>>>(h1, src, dst, h2);
    scale_kernel<<<cgrid, 256, 0, stream>>>(h2, deg);

    gemm_kernel<<<(N_NODES + TN - 1) / TN, 256, 0, stream>>>(x, h1, h2, W, b, out);
}

// Round 2
// 395.821 us; speedup vs baseline: 5.6695x; 5.6695x over previous
//
#include <hip/hip_runtime.h>

#define N_NODES 50000
#define N_EDGES 600000
#define D 128
#define K3 (3 * D)
#define TN 64
#define BK 16

// ---------------- CSR build: histogram of dst ----------------
__global__ __launch_bounds__(256) void hist_kernel(const int* __restrict__ dst,
                                                   int* __restrict__ counts) {
    int e = blockIdx.x * blockDim.x + threadIdx.x;
    if (e < N_EDGES) atomicAdd(&counts[dst[e]], 1);
}

// ---------------- single-block exclusive scan over counts[N] ----------------
// Writes off[0..N] and cursor[i]=off[i].
__global__ __launch_bounds__(1024) void scan_kernel(const int* __restrict__ counts,
                                                    int* __restrict__ off,
                                                    int* __restrict__ cursor) {
    __shared__ int lds[1024];
    const int tid = threadIdx.x;
    int carry = 0;
    for (int base = 0; base < N_NODES; base += 1024) {
        int i = base + tid;
        int v = (i < N_NODES) ? counts[i] : 0;
        lds[tid] = v;
        __syncthreads();
#pragma unroll
        for (int ofs = 1; ofs < 1024; ofs <<= 1) {
            int t = (tid >= ofs) ? lds[tid - ofs] : 0;
            __syncthreads();
            lds[tid] += t;
            __syncthreads();
        }
        int incl = lds[tid];
        int total = lds[1023];
        int excl = incl - v + carry;
        if (i < N_NODES) {
            off[i] = excl;
            cursor[i] = excl;
        }
        carry += total;
        __syncthreads();  // protect lds before next chunk's writes
    }
    if (tid == 0) off[N_NODES] = carry;
}

// ---------------- CSR fill ----------------
__global__ __launch_bounds__(256) void fill_kernel(const int* __restrict__ src,
                                                   const int* __restrict__ dst,
                                                   int* __restrict__ cursor,
                                                   int* __restrict__ csr_src) {
    int e = blockIdx.x * blockDim.x + threadIdx.x;
    if (e < N_EDGES) {
        int pos = atomicAdd(&cursor[dst[e]], 1);
        csr_src[pos] = src[e];
    }
}

// ---------------- per-node gather mean: out[n] = mean(xin[src] for src in nbrs(n)) ----
// 32 lanes per node; lane l owns floats [4l, 4l+4).
__global__ __launch_bounds__(256) void gather_kernel(const float* __restrict__ xin,
                                                     const int* __restrict__ off,
                                                     const int* __restrict__ csr_src,
                                                     float* __restrict__ out) {
    unsigned t = blockIdx.x * blockDim.x + threadIdx.x;
    unsigned n = t >> 5;
    if (n >= N_NODES) return;
    unsigned d4 = (t & 31u) << 2;
    int e0 = off[n];
    int e1 = off[n + 1];
    float4 acc = make_float4(0.f, 0.f, 0.f, 0.f);
    int e = e0;
    // 2-way unrolled: issue both index loads, then both row loads
    for (; e + 2 <= e1; e += 2) {
        int s0 = csr_src[e];
        int s1 = csr_src[e + 1];
        float4 v0 = *(const float4*)(xin + (size_t)s0 * D + d4);
        float4 v1 = *(const float4*)(xin + (size_t)s1 * D + d4);
        acc.x += v0.x + v1.x;
        acc.y += v0.y + v1.y;
        acc.z += v0.z + v1.z;
        acc.w += v0.w + v1.w;
    }
    if (e < e1) {
        int s0 = csr_src[e];
        float4 v0 = *(const float4*)(xin + (size_t)s0 * D + d4);
        acc.x += v0.x;
        acc.y += v0.y;
        acc.z += v0.z;
        acc.w += v0.w;
    }
    float inv = 1.0f / fmaxf((float)(e1 - e0), 1.0f);
    acc.x *= inv;
    acc.y *= inv;
    acc.z *= inv;
    acc.w *= inv;
    *(float4*)(out + (size_t)n * D + d4) = acc;
}

// ---------------- fp32 GEMM: out[N,128] = concat(x,h1,h2) @ W^T + b ----------------
__global__ __launch_bounds__(256) void gemm_kernel(const float* __restrict__ x,
                                                   const float* __restrict__ h1,
                                                   const float* __restrict__ h2,
                                                   const float* __restrict__ W,
                                                   const float* __restrict__ bias,
                                                   float* __restrict__ out) {
    __shared__ float fT[BK][TN + 4];  // feats tile transposed: [k][n]
    __shared__ float wT[BK][D];       // W tile transposed:     [k][o]
    const int tid = threadIdx.x;
    const int base = blockIdx.x * TN;
    const int tx = tid & 15;  // output group: outputs tx*8 .. tx*8+7
    const int ty = tid >> 4;  // node group:   nodes   ty*4 .. ty*4+3

    float acc[4][8];
#pragma unroll
    for (int j = 0; j < 4; ++j)
#pragma unroll
        for (int i = 0; i < 8; ++i) acc[j][i] = 0.0f;

    const int sr = tid >> 2;
    const int skq = (tid & 3) << 2;
    int srow = base + sr;
    if (srow >= N_NODES) srow = N_NODES - 1;

    const int o1 = tid >> 2;
    const int o2 = (tid + 256) >> 2;
    const int kq1 = (tid & 3) << 2;

    const float* segs[3] = {x, h1, h2};

    for (int k0 = 0; k0 < K3; k0 += BK) {
        const float* seg = segs[k0 >> 7];
        const int kl = k0 & (D - 1);
        float4 fv = *(const float4*)(seg + (size_t)srow * D + kl + skq);
        float4 wv1 = *(const float4*)(W + (size_t)o1 * K3 + k0 + kq1);
        float4 wv2 = *(const float4*)(W + (size_t)o2 * K3 + k0 + kq1);
        __syncthreads();
        fT[skq + 0][sr] = fv.x;
        fT[skq + 1][sr] = fv.y;
        fT[skq + 2][sr] = fv.z;
        fT[skq + 3][sr] = fv.w;
        wT[kq1 + 0][o1] = wv1.x;
        wT[kq1 + 1][o1] = wv1.y;
        wT[kq1 + 2][o1] = wv1.z;
        wT[kq1 + 3][o1] = wv1.w;
        wT[kq1 + 0][o2] = wv2.x;
        wT[kq1 + 1][o2] = wv2.y;
        wT[kq1 + 2][o2] = wv2.z;
        wT[kq1 + 3][o2] = wv2.w;
        __syncthreads();
#pragma unroll
        for (int kk = 0; kk < BK; ++kk) {
            float4 a4 = *(const float4*)&fT[kk][ty << 2];
            float4 w0 = *(const float4*)&wT[kk][tx << 3];
            float4 w1 = *(const float4*)&wT[kk][(tx << 3) + 4];
            const float a[4] = {a4.x, a4.y, a4.z, a4.w};
            const float w[8] = {w0.x, w0.y, w0.z, w0.w, w1.x, w1.y, w1.z, w1.w};
#pragma unroll
            for (int j = 0; j < 4; ++j)
#pragma unroll
                for (int i = 0; i < 8; ++i)
                    acc[j][i] = fmaf(a[j], w[i], acc[j][i]);
        }
    }

    float bv[8];
#pragma unroll
    for (int i = 0; i < 8; ++i) bv[i] = bias[(tx << 3) + i];
#pragma unroll
    for (int j = 0; j < 4; ++j) {
        int n = base + (ty << 2) + j;
        if (n < N_NODES) {
            float4 q0 = make_float4(acc[j][0] + bv[0], acc[j][1] + bv[1],
                                    acc[j][2] + bv[2], acc[j][3] + bv[3]);
            float4 q1 = make_float4(acc[j][4] + bv[4], acc[j][5] + bv[5],
                                    acc[j][6] + bv[6], acc[j][7] + bv[7]);
            *(float4*)(out + (size_t)n * D + (tx << 3)) = q0;
            *(float4*)(out + (size_t)n * D + (tx << 3) + 4) = q1;
        }
    }
}

extern "C" void kernel_launch(void* const* d_in, const int* in_sizes, int n_in,
                              void* d_out, int out_size, void* d_ws, size_t ws_size,
                              hipStream_t stream) {
    const float* x = (const float*)d_in[0];
    const int* ei = (const int*)d_in[1];
    const float* W = (const float*)d_in[2];
    const float* b = (const float*)d_in[3];
    float* out = (float*)d_out;
    const int* src = ei;            // edge_index[0,:]
    const int* dst = ei + N_EDGES;  // edge_index[1,:]

    // workspace layout:
    //   h1      [N*D]  f32   25.6 MB
    //   h2      [N*D]  f32   25.6 MB
    //   off     [N+1]  i32
    //   cursor  [N]    i32   (doubles as histogram counts)
    //   csr_src [E]    i32    2.4 MB
    float* h1 = (float*)d_ws;
    float* h2 = h1 + (size_t)N_NODES * D;
    int* off = (int*)(h2 + (size_t)N_NODES * D);
    int* cursor = off + (N_NODES + 1);
    int* csr_src = cursor + N_NODES;

    hipMemsetAsync(cursor, 0, (size_t)N_NODES * sizeof(int), stream);

    hist_kernel<<<(N_EDGES + 255) / 256, 256, 0, stream>>>(dst, cursor);
    scan_kernel<<<1, 1024, 0, stream>>>(cursor, off, cursor);
    // note: scan reads counts from cursor and overwrites cursor with offsets;
    // safe because each element is read before being written by the same thread.
    fill_kernel<<<(N_EDGES + 255) / 256, 256, 0, stream>>>(src, dst, cursor, csr_src);

    const int ggrid = ((N_NODES * 32) + 255) / 256;
    gather_kernel<<<ggrid, 256, 0, stream>>>(x, off, csr_src, h1);
    gather_kernel<<<ggrid, 256, 0, stream>>>(h1, off, csr_src, h2);

    gemm_kernel<<<(N_NODES + TN - 1) / TN, 256, 0, stream>>>(x, h1, h2, W, b, out);
}

// Round 3
// 258.139 us; speedup vs baseline: 8.6934x; 1.5334x over previous
//
#include <hip/hip_runtime.h>

#define N_NODES 50000
#define N_EDGES 600000
#define D 128
#define K3 (3 * D)

typedef __attribute__((ext_vector_type(8))) short short8;
typedef __attribute__((ext_vector_type(4))) float floatx4;
typedef __attribute__((ext_vector_type(8))) unsigned short ushort8;

static __device__ __forceinline__ unsigned short f2bf(float f) {
    unsigned u = __float_as_uint(f);
    u += 0x7fff + ((u >> 16) & 1);  // RNE
    return (unsigned short)(u >> 16);
}
static __device__ __forceinline__ float bf2f(unsigned short s) {
    return __uint_as_float(((unsigned)s) << 16);
}

// ---------------- CSR build: histogram of dst ----------------
__global__ __launch_bounds__(256) void hist_kernel(const int* __restrict__ dst,
                                                   int* __restrict__ counts) {
    int e = blockIdx.x * blockDim.x + threadIdx.x;
    if (e < N_EDGES) atomicAdd(&counts[dst[e]], 1);
}

// ---------------- 3-phase scan ----------------
__global__ __launch_bounds__(256) void bsum_kernel(const int* __restrict__ counts,
                                                   int* __restrict__ bsum) {
    __shared__ int wsum[4];
    int tid = threadIdx.x;
    int i = blockIdx.x * 256 + tid;
    int v = (i < N_NODES) ? counts[i] : 0;
#pragma unroll
    for (int d = 32; d >= 1; d >>= 1) v += __shfl_xor(v, d);
    if ((tid & 63) == 0) wsum[tid >> 6] = v;
    __syncthreads();
    if (tid == 0) bsum[blockIdx.x] = wsum[0] + wsum[1] + wsum[2] + wsum[3];
}

// single block: exclusive scan of bsum[0..nb) -> bexcl; also off[N_NODES]=N_EDGES
__global__ __launch_bounds__(256) void scan_bsum_kernel(const int* __restrict__ bsum,
                                                        int* __restrict__ bexcl,
                                                        int* __restrict__ off, int nb) {
    __shared__ int wsum[4];
    int tid = threadIdx.x;
    int lane = tid & 63, wid = tid >> 6;
    int v = (tid < nb) ? bsum[tid] : 0;
    int x = v;
#pragma unroll
    for (int d = 1; d < 64; d <<= 1) {
        int u = __shfl_up(x, d);
        if (lane >= d) x += u;
    }
    if (lane == 63) wsum[wid] = x;
    __syncthreads();
    int prefix = 0;
    for (int w = 0; w < wid; ++w) prefix += wsum[w];
    if (tid < nb) bexcl[tid] = prefix + x - v;
    if (tid == 0) off[N_NODES] = N_EDGES;
}

__global__ __launch_bounds__(256) void scan_final_kernel(const int* __restrict__ counts,
                                                         const int* __restrict__ bexcl,
                                                         int* __restrict__ off,
                                                         int* __restrict__ cursor) {
    __shared__ int wsum[4];
    int tid = threadIdx.x;
    int lane = tid & 63, wid = tid >> 6;
    int i = blockIdx.x * 256 + tid;
    int v = (i < N_NODES) ? counts[i] : 0;
    int x = v;
#pragma unroll
    for (int d = 1; d < 64; d <<= 1) {
        int u = __shfl_up(x, d);
        if (lane >= d) x += u;
    }
    if (lane == 63) wsum[wid] = x;
    __syncthreads();
    int prefix = 0;
    for (int w = 0; w < wid; ++w) prefix += wsum[w];
    if (i < N_NODES) {
        int excl = bexcl[blockIdx.x] + prefix + x - v;
        off[i] = excl;
        cursor[i] = excl;
    }
}

// ---------------- CSR fill ----------------
__global__ __launch_bounds__(256) void fill_kernel(const int* __restrict__ src,
                                                   const int* __restrict__ dst,
                                                   int* __restrict__ cursor,
                                                   int* __restrict__ csr_src) {
    int e = blockIdx.x * blockDim.x + threadIdx.x;
    if (e < N_EDGES) {
        int pos = atomicAdd(&cursor[dst[e]], 1);
        csr_src[pos] = src[e];
    }
}

// ---------------- convert x -> bf16 into feats[:, 0:128] ----------------
__global__ __launch_bounds__(256) void convert_x_kernel(const float* __restrict__ x,
                                                        unsigned short* __restrict__ feats) {
    unsigned t = blockIdx.x * blockDim.x + threadIdx.x;
    if (t >= (unsigned)N_NODES * (D / 8)) return;
    unsigned n = t >> 4;          // 16 chunks of 8 per row
    unsigned c = (t & 15u) << 3;  // element offset 0..120
    const float4 v0 = *(const float4*)(x + (size_t)n * D + c);
    const float4 v1 = *(const float4*)(x + (size_t)n * D + c + 4);
    ushort8 o;
    o[0] = f2bf(v0.x); o[1] = f2bf(v0.y); o[2] = f2bf(v0.z); o[3] = f2bf(v0.w);
    o[4] = f2bf(v1.x); o[5] = f2bf(v1.y); o[6] = f2bf(v1.z); o[7] = f2bf(v1.w);
    *(ushort8*)(feats + (size_t)n * K3 + c) = o;
}

// ---------------- convert W -> bf16 (same [128][384] layout) ----------------
__global__ __launch_bounds__(256) void convert_w_kernel(const float* __restrict__ W,
                                                        unsigned short* __restrict__ Wb) {
    unsigned t = blockIdx.x * blockDim.x + threadIdx.x;
    if (t >= (D * K3) / 8) return;
    unsigned e = t << 3;
    const float4 v0 = *(const float4*)(W + e);
    const float4 v1 = *(const float4*)(W + e + 4);
    ushort8 o;
    o[0] = f2bf(v0.x); o[1] = f2bf(v0.y); o[2] = f2bf(v0.z); o[3] = f2bf(v0.w);
    o[4] = f2bf(v1.x); o[5] = f2bf(v1.y); o[6] = f2bf(v1.z); o[7] = f2bf(v1.w);
    *(ushort8*)(Wb + e) = o;
}

// ---------------- bf16 gather-mean within packed feats ----------------
// 16 lanes per node, lane owns 8 bf16 (16 B). Reads cols [inCol,inCol+128),
// writes cols [outCol,outCol+128).
__global__ __launch_bounds__(256) void gather_kernel(unsigned short* __restrict__ feats,
                                                     const int* __restrict__ off,
                                                     const int* __restrict__ csr_src,
                                                     int inCol, int outCol) {
    unsigned t = blockIdx.x * blockDim.x + threadIdx.x;
    unsigned n = t >> 4;
    if (n >= N_NODES) return;
    unsigned c = (t & 15u) << 3;
    const unsigned short* fin = feats + inCol + c;
    int e0 = off[n];
    int e1 = off[n + 1];
    float acc[8] = {0.f, 0.f, 0.f, 0.f, 0.f, 0.f, 0.f, 0.f};
    int e = e0;
    for (; e + 2 <= e1; e += 2) {
        int s0 = csr_src[e];
        int s1 = csr_src[e + 1];
        ushort8 v0 = *(const ushort8*)(fin + (size_t)s0 * K3);
        ushort8 v1 = *(const ushort8*)(fin + (size_t)s1 * K3);
#pragma unroll
        for (int j = 0; j < 8; ++j) acc[j] += bf2f(v0[j]) + bf2f(v1[j]);
    }
    if (e < e1) {
        int s0 = csr_src[e];
        ushort8 v0 = *(const ushort8*)(fin + (size_t)s0 * K3);
#pragma unroll
        for (int j = 0; j < 8; ++j) acc[j] += bf2f(v0[j]);
    }
    float inv = 1.0f / fmaxf((float)(e1 - e0), 1.0f);
    ushort8 o;
#pragma unroll
    for (int j = 0; j < 8; ++j) o[j] = f2bf(acc[j] * inv);
    *(ushort8*)(feats + (size_t)n * K3 + outCol + c) = o;
}

// ---------------- bf16 MFMA GEMM: out[N,128] = feats[N,384] @ Wb^T + b ----------------
// 256 threads = 4 waves; block tile 64 rows; each wave: 16 rows x 128 cols.
// A-frag: A[m=lane&15][k=quad*8+j]; B-frag: B[k=quad*8+j][n=lane&15] = Wb[n][k].
// C/D: col=lane&15, row=quad*4+reg.
__global__ __launch_bounds__(256) void gemm_mfma_kernel(const unsigned short* __restrict__ feats,
                                                        const unsigned short* __restrict__ Wb,
                                                        const float* __restrict__ bias,
                                                        float* __restrict__ out) {
    const int tid = threadIdx.x;
    const int wave = tid >> 6;
    const int lane = tid & 63;
    const int col = lane & 15;
    const int quad = lane >> 4;
    const int mbase = blockIdx.x * 64 + wave * 16;

    int arow = mbase + col;
    if (arow >= N_NODES) arow = N_NODES - 1;  // clamp loads; stores guarded
    const unsigned short* aptr = feats + (size_t)arow * K3 + quad * 8;
    const unsigned short* bptr = Wb + (size_t)col * K3 + quad * 8;

    floatx4 acc[8];
#pragma unroll
    for (int t = 0; t < 8; ++t) acc[t] = (floatx4){0.f, 0.f, 0.f, 0.f};

#pragma unroll
    for (int ks = 0; ks < K3 / 32; ++ks) {
        short8 a = *(const short8*)(aptr + ks * 32);
#pragma unroll
        for (int t = 0; t < 8; ++t) {
            short8 b = *(const short8*)(bptr + (size_t)t * 16 * K3 + ks * 32);
            acc[t] = __builtin_amdgcn_mfma_f32_16x16x32_bf16(a, b, acc[t], 0, 0, 0);
        }
    }

#pragma unroll
    for (int t = 0; t < 8; ++t) {
        float bv = bias[t * 16 + col];
#pragma unroll
        for (int r = 0; r < 4; ++r) {
            int orow = mbase + quad * 4 + r;
            if (orow < N_NODES)
                out[(size_t)orow * D + t * 16 + col] = acc[t][r] + bv;
        }
    }
}

extern "C" void kernel_launch(void* const* d_in, const int* in_sizes, int n_in,
                              void* d_out, int out_size, void* d_ws, size_t ws_size,
                              hipStream_t stream) {
    const float* x = (const float*)d_in[0];
    const int* ei = (const int*)d_in[1];
    const float* W = (const float*)d_in[2];
    const float* b = (const float*)d_in[3];
    float* out = (float*)d_out;
    const int* src = ei;            // edge_index[0,:]
    const int* dst = ei + N_EDGES;  // edge_index[1,:]

    // workspace layout:
    //   feats   [N][384] bf16  38.4 MB  (cols 0-127 = x, 128-255 = hop1, 256-383 = hop2)
    //   Wb      [128][384] bf16  98.3 KB
    //   off     [N+1] i32
    //   cursor  [N]   i32  (doubles as histogram counts)
    //   bsum/bexcl [196+196] i32
    //   csr_src [E]   i32   2.4 MB
    unsigned short* feats = (unsigned short*)d_ws;
    unsigned short* Wb = feats + (size_t)N_NODES * K3;
    int* off = (int*)(Wb + (size_t)D * K3);
    int* cursor = off + (N_NODES + 1);
    int* bsum = cursor + N_NODES;
    int* bexcl = bsum + 256;
    int* csr_src = bexcl + 256;

    const int NB = (N_NODES + 255) / 256;  // 196 scan blocks

    hipMemsetAsync(cursor, 0, (size_t)N_NODES * sizeof(int), stream);

    convert_x_kernel<<<(N_NODES * 16 + 255) / 256, 256, 0, stream>>>(x, feats);
    convert_w_kernel<<<((D * K3) / 8 + 255) / 256, 256, 0, stream>>>(W, Wb);

    hist_kernel<<<(N_EDGES + 255) / 256, 256, 0, stream>>>(dst, cursor);
    bsum_kernel<<<NB, 256, 0, stream>>>(cursor, bsum);
    scan_bsum_kernel<<<1, 256, 0, stream>>>(bsum, bexcl, off, NB);
    scan_final_kernel<<<NB, 256, 0, stream>>>(cursor, bexcl, off, cursor);
    fill_kernel<<<(N_EDGES + 255) / 256, 256, 0, stream>>>(src, dst, cursor, csr_src);

    const int ggrid = (N_NODES * 16 + 255) / 256;
    gather_kernel<<<ggrid, 256, 0, stream>>>(feats, off, csr_src, 0, D);
    gather_kernel<<<ggrid, 256, 0, stream>>>(feats, off, csr_src, D, 2 * D);

    gemm_mfma_kernel<<<(N_NODES + 63) / 64, 256, 0, stream>>>(feats, Wb, b, out);
}

// Round 4
// 224.513 us; speedup vs baseline: 9.9954x; 1.1498x over previous
//
#include <hip/hip_runtime.h>

#define N_NODES 50000
#define N_EDGES 600000
#define D 128
#define K3 (3 * D)

typedef __attribute__((ext_vector_type(8))) short short8;
typedef __attribute__((ext_vector_type(4))) float floatx4;
typedef __attribute__((ext_vector_type(8))) unsigned short ushort8;

static __device__ __forceinline__ unsigned short f2bf(float f) {
    unsigned u = __float_as_uint(f);
    u += 0x7fff + ((u >> 16) & 1);  // RNE
    return (unsigned short)(u >> 16);
}
static __device__ __forceinline__ float bf2f(unsigned short s) {
    return __uint_as_float(((unsigned)s) << 16);
}

// ---------------- CSR build: histogram of dst ----------------
__global__ __launch_bounds__(256) void hist_kernel(const int* __restrict__ dst,
                                                   int* __restrict__ counts) {
    int e = blockIdx.x * blockDim.x + threadIdx.x;
    if (e < N_EDGES) atomicAdd(&counts[dst[e]], 1);
}

// ---------------- 3-phase scan ----------------
__global__ __launch_bounds__(256) void bsum_kernel(const int* __restrict__ counts,
                                                   int* __restrict__ bsum) {
    __shared__ int wsum[4];
    int tid = threadIdx.x;
    int i = blockIdx.x * 256 + tid;
    int v = (i < N_NODES) ? counts[i] : 0;
#pragma unroll
    for (int d = 32; d >= 1; d >>= 1) v += __shfl_xor(v, d);
    if ((tid & 63) == 0) wsum[tid >> 6] = v;
    __syncthreads();
    if (tid == 0) bsum[blockIdx.x] = wsum[0] + wsum[1] + wsum[2] + wsum[3];
}

__global__ __launch_bounds__(256) void scan_bsum_kernel(const int* __restrict__ bsum,
                                                        int* __restrict__ bexcl,
                                                        int* __restrict__ off, int nb) {
    __shared__ int wsum[4];
    int tid = threadIdx.x;
    int lane = tid & 63, wid = tid >> 6;
    int v = (tid < nb) ? bsum[tid] : 0;
    int x = v;
#pragma unroll
    for (int d = 1; d < 64; d <<= 1) {
        int u = __shfl_up(x, d);
        if (lane >= d) x += u;
    }
    if (lane == 63) wsum[wid] = x;
    __syncthreads();
    int prefix = 0;
    for (int w = 0; w < wid; ++w) prefix += wsum[w];
    if (tid < nb) bexcl[tid] = prefix + x - v;
    if (tid == 0) off[N_NODES] = N_EDGES;
}

__global__ __launch_bounds__(256) void scan_final_kernel(const int* __restrict__ counts,
                                                         const int* __restrict__ bexcl,
                                                         int* __restrict__ off,
                                                         int* __restrict__ cursor) {
    __shared__ int wsum[4];
    int tid = threadIdx.x;
    int lane = tid & 63, wid = tid >> 6;
    int i = blockIdx.x * 256 + tid;
    int v = (i < N_NODES) ? counts[i] : 0;
    int x = v;
#pragma unroll
    for (int d = 1; d < 64; d <<= 1) {
        int u = __shfl_up(x, d);
        if (lane >= d) x += u;
    }
    if (lane == 63) wsum[wid] = x;
    __syncthreads();
    int prefix = 0;
    for (int w = 0; w < wid; ++w) prefix += wsum[w];
    if (i < N_NODES) {
        int excl = bexcl[blockIdx.x] + prefix + x - v;
        off[i] = excl;
        cursor[i] = excl;
    }
}

// ---------------- CSR fill ----------------
__global__ __launch_bounds__(256) void fill_kernel(const int* __restrict__ src,
                                                   const int* __restrict__ dst,
                                                   int* __restrict__ cursor,
                                                   int* __restrict__ csr_src) {
    int e = blockIdx.x * blockDim.x + threadIdx.x;
    if (e < N_EDGES) {
        int pos = atomicAdd(&cursor[dst[e]], 1);
        csr_src[pos] = src[e];
    }
}

// ---------------- convert x -> bf16 into feats[:, 0:128] ----------------
__global__ __launch_bounds__(256) void convert_x_kernel(const float* __restrict__ x,
                                                        unsigned short* __restrict__ feats) {
    unsigned t = blockIdx.x * blockDim.x + threadIdx.x;
    if (t >= (unsigned)N_NODES * (D / 8)) return;
    unsigned n = t >> 4;
    unsigned c = (t & 15u) << 3;
    const float4 v0 = *(const float4*)(x + (size_t)n * D + c);
    const float4 v1 = *(const float4*)(x + (size_t)n * D + c + 4);
    ushort8 o;
    o[0] = f2bf(v0.x); o[1] = f2bf(v0.y); o[2] = f2bf(v0.z); o[3] = f2bf(v0.w);
    o[4] = f2bf(v1.x); o[5] = f2bf(v1.y); o[6] = f2bf(v1.z); o[7] = f2bf(v1.w);
    *(ushort8*)(feats + (size_t)n * K3 + c) = o;
}

// ---------------- convert W -> frag-ordered bf16 Wr ----------------
// chunk id = (ks*8 + t)*64 + lane  (16 B each);  lane: c=lane&15, q=lane>>4
// chunk[j] = W[16*t + c][ks*32 + q*8 + j]   -> B-frag for MFMA(t, ks) at `lane`
__global__ __launch_bounds__(256) void convert_w_kernel(const float* __restrict__ W,
                                                        unsigned short* __restrict__ Wr) {
    unsigned id = blockIdx.x * blockDim.x + threadIdx.x;  // 6144 chunks
    if (id >= 12u * 8u * 64u) return;
    unsigned ks = id >> 9;
    unsigned t = (id >> 6) & 7u;
    unsigned lane = id & 63u;
    unsigned c = lane & 15u;
    unsigned q = lane >> 4;
    unsigned row = 16u * t + c;
    unsigned k = ks * 32u + q * 8u;
    const float4 v0 = *(const float4*)(W + (size_t)row * K3 + k);
    const float4 v1 = *(const float4*)(W + (size_t)row * K3 + k + 4);
    ushort8 o;
    o[0] = f2bf(v0.x); o[1] = f2bf(v0.y); o[2] = f2bf(v0.z); o[3] = f2bf(v0.w);
    o[4] = f2bf(v1.x); o[5] = f2bf(v1.y); o[6] = f2bf(v1.z); o[7] = f2bf(v1.w);
    *(ushort8*)(Wr + (size_t)id * 8) = o;
}

// ---------------- bf16 gather-mean within packed feats ----------------
// 16 lanes per node; 4-way unrolled edge loop for load ILP.
__global__ __launch_bounds__(256) void gather_kernel(unsigned short* __restrict__ feats,
                                                     const int* __restrict__ off,
                                                     const int* __restrict__ csr_src,
                                                     int inCol, int outCol) {
    unsigned t = blockIdx.x * blockDim.x + threadIdx.x;
    unsigned n = t >> 4;
    if (n >= N_NODES) return;
    unsigned c = (t & 15u) << 3;
    const unsigned short* fin = feats + inCol + c;
    int e0 = off[n];
    int e1 = off[n + 1];
    float acc[8] = {0.f, 0.f, 0.f, 0.f, 0.f, 0.f, 0.f, 0.f};
    int e = e0;
    for (; e + 4 <= e1; e += 4) {
        int s0 = csr_src[e];
        int s1 = csr_src[e + 1];
        int s2 = csr_src[e + 2];
        int s3 = csr_src[e + 3];
        ushort8 v0 = *(const ushort8*)(fin + (size_t)s0 * K3);
        ushort8 v1 = *(const ushort8*)(fin + (size_t)s1 * K3);
        ushort8 v2 = *(const ushort8*)(fin + (size_t)s2 * K3);
        ushort8 v3 = *(const ushort8*)(fin + (size_t)s3 * K3);
#pragma unroll
        for (int j = 0; j < 8; ++j)
            acc[j] += (bf2f(v0[j]) + bf2f(v1[j])) + (bf2f(v2[j]) + bf2f(v3[j]));
    }
    if (e + 2 <= e1) {
        int s0 = csr_src[e];
        int s1 = csr_src[e + 1];
        ushort8 v0 = *(const ushort8*)(fin + (size_t)s0 * K3);
        ushort8 v1 = *(const ushort8*)(fin + (size_t)s1 * K3);
#pragma unroll
        for (int j = 0; j < 8; ++j) acc[j] += bf2f(v0[j]) + bf2f(v1[j]);
        e += 2;
    }
    if (e < e1) {
        int s0 = csr_src[e];
        ushort8 v0 = *(const ushort8*)(fin + (size_t)s0 * K3);
#pragma unroll
        for (int j = 0; j < 8; ++j) acc[j] += bf2f(v0[j]);
    }
    float inv = 1.0f / fmaxf((float)(e1 - e0), 1.0f);
    ushort8 o;
#pragma unroll
    for (int j = 0; j < 8; ++j) o[j] = f2bf(acc[j] * inv);
    *(ushort8*)(feats + (size_t)n * K3 + outCol + c) = o;
}

// ---------------- bf16 MFMA GEMM: out[N,128] = feats[N,384] @ W^T + b ----------------
// 4 waves/block; wave tile = 32 rows x 128 cols (2 rowblocks x 8 colblocks).
// B-frags from frag-ordered Wr: coalesced 1KB wave loads, L2-resident.
// No LDS, no barriers — pure register pipeline.
__global__ __launch_bounds__(256) void gemm_mfma_kernel(const unsigned short* __restrict__ feats,
                                                        const unsigned short* __restrict__ Wr,
                                                        const float* __restrict__ bias,
                                                        float* __restrict__ out) {
    const int tid = threadIdx.x;
    const int wave = tid >> 6;
    const int lane = tid & 63;
    const int col = lane & 15;
    const int quad = lane >> 4;
    const int mbase = blockIdx.x * 128 + wave * 32;

    int r0 = mbase + col;
    int r1 = mbase + 16 + col;
    if (r0 >= N_NODES) r0 = N_NODES - 1;
    if (r1 >= N_NODES) r1 = N_NODES - 1;
    const unsigned short* aptr0 = feats + (size_t)r0 * K3 + quad * 8;
    const unsigned short* aptr1 = feats + (size_t)r1 * K3 + quad * 8;
    const unsigned short* wptr = Wr + (size_t)lane * 8;  // + chunk*512 elements

    floatx4 acc0[8], acc1[8];
#pragma unroll
    for (int t = 0; t < 8; ++t) {
        acc0[t] = (floatx4){0.f, 0.f, 0.f, 0.f};
        acc1[t] = (floatx4){0.f, 0.f, 0.f, 0.f};
    }

#pragma unroll
    for (int ks = 0; ks < 12; ++ks) {
        short8 a0 = *(const short8*)(aptr0 + ks * 32);
        short8 a1 = *(const short8*)(aptr1 + ks * 32);
        short8 b[8];
#pragma unroll
        for (int t = 0; t < 8; ++t)
            b[t] = *(const short8*)(wptr + (size_t)(ks * 8 + t) * 512);
#pragma unroll
        for (int t = 0; t < 8; ++t) {
            acc0[t] = __builtin_amdgcn_mfma_f32_16x16x32_bf16(a0, b[t], acc0[t], 0, 0, 0);
            acc1[t] = __builtin_amdgcn_mfma_f32_16x16x32_bf16(a1, b[t], acc1[t], 0, 0, 0);
        }
    }

#pragma unroll
    for (int t = 0; t < 8; ++t) {
        float bv = bias[t * 16 + col];
#pragma unroll
        for (int r = 0; r < 4; ++r) {
            int o0 = mbase + quad * 4 + r;
            int o1 = mbase + 16 + quad * 4 + r;
            if (o0 < N_NODES) out[(size_t)o0 * D + t * 16 + col] = acc0[t][r] + bv;
            if (o1 < N_NODES) out[(size_t)o1 * D + t * 16 + col] = acc1[t][r] + bv;
        }
    }
}

extern "C" void kernel_launch(void* const* d_in, const int* in_sizes, int n_in,
                              void* d_out, int out_size, void* d_ws, size_t ws_size,
                              hipStream_t stream) {
    const float* x = (const float*)d_in[0];
    const int* ei = (const int*)d_in[1];
    const float* W = (const float*)d_in[2];
    const float* b = (const float*)d_in[3];
    float* out = (float*)d_out;
    const int* src = ei;            // edge_index[0,:]
    const int* dst = ei + N_EDGES;  // edge_index[1,:]

    // workspace layout:
    //   feats   [N][384] bf16  38.4 MB (cols 0-127 = x, 128-255 = hop1, 256-383 = hop2)
    //   Wr      frag-ordered W bf16, 6144 chunks x 16 B = 98.3 KB
    //   off     [N+1] i32 | cursor [N] i32 | bsum/bexcl | csr_src [E] i32
    unsigned short* feats = (unsigned short*)d_ws;
    unsigned short* Wr = feats + (size_t)N_NODES * K3;
    int* off = (int*)(Wr + (size_t)D * K3);
    int* cursor = off + (N_NODES + 1);
    int* bsum = cursor + N_NODES;
    int* bexcl = bsum + 256;
    int* csr_src = bexcl + 256;

    const int NB = (N_NODES + 255) / 256;

    hipMemsetAsync(cursor, 0, (size_t)N_NODES * sizeof(int), stream);

    convert_x_kernel<<<(N_NODES * 16 + 255) / 256, 256, 0, stream>>>(x, feats);
    convert_w_kernel<<<(12 * 8 * 64 + 255) / 256, 256, 0, stream>>>(W, Wr);

    hist_kernel<<<(N_EDGES + 255) / 256, 256, 0, stream>>>(dst, cursor);
    bsum_kernel<<<NB, 256, 0, stream>>>(cursor, bsum);
    scan_bsum_kernel<<<1, 256, 0, stream>>>(bsum, bexcl, off, NB);
    scan_final_kernel<<<NB, 256, 0, stream>>>(cursor, bexcl, off, cursor);
    fill_kernel<<<(N_EDGES + 255) / 256, 256, 0, stream>>>(src, dst, cursor, csr_src);

    const int ggrid = (N_NODES * 16 + 255) / 256;
    gather_kernel<<<ggrid, 256, 0, stream>>>(feats, off, csr_src, 0, D);
    gather_kernel<<<ggrid, 256, 0, stream>>>(feats, off, csr_src, D, 2 * D);

    gemm_mfma_kernel<<<(N_NODES + 127) / 128, 256, 0, stream>>>(feats, Wr, b, out);
}

// Round 5
// 219.795 us; speedup vs baseline: 10.2100x; 1.0215x over previous
//
#include <hip/hip_runtime.h>

#define N_NODES 50000
#define N_EDGES 600000
#define D 128
#define K3 (3 * D)

typedef __attribute__((ext_vector_type(8))) short short8;
typedef __attribute__((ext_vector_type(4))) float floatx4;
typedef __attribute__((ext_vector_type(8))) unsigned short ushort8;

static __device__ __forceinline__ unsigned short f2bf(float f) {
    unsigned u = __float_as_uint(f);
    u += 0x7fff + ((u >> 16) & 1);  // RNE
    return (unsigned short)(u >> 16);
}
static __device__ __forceinline__ float bf2f(unsigned short s) {
    return __uint_as_float(((unsigned)s) << 16);
}

// ---------------- fused setup: convert_x | convert_w | hist ----------------
// blocks [0,3125): x->bf16 into feats[:,0:128]
// blocks [3125,3149): W->frag-ordered Wr
// blocks [3149,5493): histogram of dst into counts
__global__ __launch_bounds__(256) void setup_kernel(const float* __restrict__ x,
                                                    const float* __restrict__ W,
                                                    const int* __restrict__ dst,
                                                    unsigned short* __restrict__ feats,
                                                    unsigned short* __restrict__ Wr,
                                                    int* __restrict__ counts) {
    const int b = blockIdx.x;
    const int tid = threadIdx.x;
    if (b < 3125) {
        unsigned t = b * 256 + tid;  // exactly 50000*16
        unsigned n = t >> 4;
        unsigned c = (t & 15u) << 3;
        const float4 v0 = *(const float4*)(x + (size_t)n * D + c);
        const float4 v1 = *(const float4*)(x + (size_t)n * D + c + 4);
        ushort8 o;
        o[0] = f2bf(v0.x); o[1] = f2bf(v0.y); o[2] = f2bf(v0.z); o[3] = f2bf(v0.w);
        o[4] = f2bf(v1.x); o[5] = f2bf(v1.y); o[6] = f2bf(v1.z); o[7] = f2bf(v1.w);
        *(ushort8*)(feats + (size_t)n * K3 + c) = o;
    } else if (b < 3149) {
        unsigned id = (b - 3125) * 256 + tid;  // exactly 6144 chunks
        unsigned ks = id >> 9;
        unsigned t8 = (id >> 6) & 7u;
        unsigned lane = id & 63u;
        unsigned c = lane & 15u;
        unsigned q = lane >> 4;
        unsigned row = 16u * t8 + c;
        unsigned k = ks * 32u + q * 8u;
        const float4 v0 = *(const float4*)(W + (size_t)row * K3 + k);
        const float4 v1 = *(const float4*)(W + (size_t)row * K3 + k + 4);
        ushort8 o;
        o[0] = f2bf(v0.x); o[1] = f2bf(v0.y); o[2] = f2bf(v0.z); o[3] = f2bf(v0.w);
        o[4] = f2bf(v1.x); o[5] = f2bf(v1.y); o[6] = f2bf(v1.z); o[7] = f2bf(v1.w);
        *(ushort8*)(Wr + (size_t)id * 8) = o;
    } else {
        int e = (b - 3149) * 256 + tid;
        if (e < N_EDGES) atomicAdd(&counts[dst[e]], 1);
    }
}

// ---------------- 3-phase scan ----------------
__global__ __launch_bounds__(256) void bsum_kernel(const int* __restrict__ counts,
                                                   int* __restrict__ bsum) {
    __shared__ int wsum[4];
    int tid = threadIdx.x;
    int i = blockIdx.x * 256 + tid;
    int v = (i < N_NODES) ? counts[i] : 0;
#pragma unroll
    for (int d = 32; d >= 1; d >>= 1) v += __shfl_xor(v, d);
    if ((tid & 63) == 0) wsum[tid >> 6] = v;
    __syncthreads();
    if (tid == 0) bsum[blockIdx.x] = wsum[0] + wsum[1] + wsum[2] + wsum[3];
}

__global__ __launch_bounds__(256) void scan_bsum_kernel(const int* __restrict__ bsum,
                                                        int* __restrict__ bexcl,
                                                        int* __restrict__ off, int nb) {
    __shared__ int wsum[4];
    int tid = threadIdx.x;
    int lane = tid & 63, wid = tid >> 6;
    int v = (tid < nb) ? bsum[tid] : 0;
    int x = v;
#pragma unroll
    for (int d = 1; d < 64; d <<= 1) {
        int u = __shfl_up(x, d);
        if (lane >= d) x += u;
    }
    if (lane == 63) wsum[wid] = x;
    __syncthreads();
    int prefix = 0;
    for (int w = 0; w < wid; ++w) prefix += wsum[w];
    if (tid < nb) bexcl[tid] = prefix + x - v;
    if (tid == 0) off[N_NODES] = N_EDGES;
}

__global__ __launch_bounds__(256) void scan_final_kernel(const int* __restrict__ counts,
                                                         const int* __restrict__ bexcl,
                                                         int* __restrict__ off,
                                                         int* __restrict__ cursor) {
    __shared__ int wsum[4];
    int tid = threadIdx.x;
    int lane = tid & 63, wid = tid >> 6;
    int i = blockIdx.x * 256 + tid;
    int v = (i < N_NODES) ? counts[i] : 0;
    int x = v;
#pragma unroll
    for (int d = 1; d < 64; d <<= 1) {
        int u = __shfl_up(x, d);
        if (lane >= d) x += u;
    }
    if (lane == 63) wsum[wid] = x;
    __syncthreads();
    int prefix = 0;
    for (int w = 0; w < wid; ++w) prefix += wsum[w];
    if (i < N_NODES) {
        int excl = bexcl[blockIdx.x] + prefix + x - v;
        off[i] = excl;
        cursor[i] = excl;
    }
}

// ---------------- CSR fill ----------------
__global__ __launch_bounds__(256) void fill_kernel(const int* __restrict__ src,
                                                   const int* __restrict__ dst,
                                                   int* __restrict__ cursor,
                                                   int* __restrict__ csr_src) {
    int e = blockIdx.x * blockDim.x + threadIdx.x;
    if (e < N_EDGES) {
        int pos = atomicAdd(&cursor[dst[e]], 1);
        csr_src[pos] = src[e];
    }
}

// ---------------- bf16 gather-mean, one WAVE per node ----------------
// lane = slot*16 + colchunk: slot s in [0,4) owns edges e0+s, e0+s+4, ...;
// colchunk owns 8 bf16 (16 B). 4 independent row-loads in flight per iteration;
// per-node divergence only (no max-of-4-nodes penalty). Cross-slot reduce via
// shfl_xor(16/32); lanes 0-15 store the row.
__global__ __launch_bounds__(256) void gather_kernel(unsigned short* __restrict__ feats,
                                                     const int* __restrict__ off,
                                                     const int* __restrict__ csr_src,
                                                     int inCol, int outCol) {
    unsigned n = (blockIdx.x * 256 + threadIdx.x) >> 6;
    if (n >= N_NODES) return;
    const int lane = threadIdx.x & 63;
    const int s = lane >> 4;
    const unsigned c = (lane & 15u) << 3;
    const unsigned short* fin = feats + inCol + c;
    const int e0 = off[n];
    const int e1 = off[n + 1];
    float acc[8] = {0.f, 0.f, 0.f, 0.f, 0.f, 0.f, 0.f, 0.f};
    for (int e = e0 + s; e < e1; e += 16) {
        // 4 edges for this slot per iteration (deg<=16 -> single iteration)
        const int i1 = e + 4, i2 = e + 8, i3 = e + 12;
        int s0 = csr_src[e];
        int s1 = (i1 < e1) ? csr_src[i1] : s0;
        int s2 = (i2 < e1) ? csr_src[i2] : s0;
        int s3 = (i3 < e1) ? csr_src[i3] : s0;
        float m1 = (i1 < e1) ? 1.f : 0.f;
        float m2 = (i2 < e1) ? 1.f : 0.f;
        float m3 = (i3 < e1) ? 1.f : 0.f;
        ushort8 v0 = *(const ushort8*)(fin + (size_t)s0 * K3);
        ushort8 v1 = *(const ushort8*)(fin + (size_t)s1 * K3);
        ushort8 v2 = *(const ushort8*)(fin + (size_t)s2 * K3);
        ushort8 v3 = *(const ushort8*)(fin + (size_t)s3 * K3);
#pragma unroll
        for (int j = 0; j < 8; ++j) {
            float t0 = bf2f(v0[j]) + m1 * bf2f(v1[j]);
            float t1 = m2 * bf2f(v2[j]) + m3 * bf2f(v3[j]);
            acc[j] += t0 + t1;
        }
    }
#pragma unroll
    for (int j = 0; j < 8; ++j) {
        acc[j] += __shfl_xor(acc[j], 16);
        acc[j] += __shfl_xor(acc[j], 32);
    }
    if (s == 0) {
        float inv = 1.0f / fmaxf((float)(e1 - e0), 1.0f);
        ushort8 o;
#pragma unroll
        for (int j = 0; j < 8; ++j) o[j] = f2bf(acc[j] * inv);
        *(ushort8*)(feats + (size_t)n * K3 + outCol + c) = o;
    }
}

// ---------------- bf16 MFMA GEMM: out[N,128] = feats[N,384] @ W^T + b ----------------
// 4 waves/block; wave tile = 32 rows x 128 cols. B-frags from frag-ordered Wr.
__global__ __launch_bounds__(256) void gemm_mfma_kernel(const unsigned short* __restrict__ feats,
                                                        const unsigned short* __restrict__ Wr,
                                                        const float* __restrict__ bias,
                                                        float* __restrict__ out) {
    const int tid = threadIdx.x;
    const int wave = tid >> 6;
    const int lane = tid & 63;
    const int col = lane & 15;
    const int quad = lane >> 4;
    const int mbase = blockIdx.x * 128 + wave * 32;

    int r0 = mbase + col;
    int r1 = mbase + 16 + col;
    if (r0 >= N_NODES) r0 = N_NODES - 1;
    if (r1 >= N_NODES) r1 = N_NODES - 1;
    const unsigned short* aptr0 = feats + (size_t)r0 * K3 + quad * 8;
    const unsigned short* aptr1 = feats + (size_t)r1 * K3 + quad * 8;
    const unsigned short* wptr = Wr + (size_t)lane * 8;

    floatx4 acc0[8], acc1[8];
#pragma unroll
    for (int t = 0; t < 8; ++t) {
        acc0[t] = (floatx4){0.f, 0.f, 0.f, 0.f};
        acc1[t] = (floatx4){0.f, 0.f, 0.f, 0.f};
    }

#pragma unroll
    for (int ks = 0; ks < 12; ++ks) {
        short8 a0 = *(const short8*)(aptr0 + ks * 32);
        short8 a1 = *(const short8*)(aptr1 + ks * 32);
        short8 b[8];
#pragma unroll
        for (int t = 0; t < 8; ++t)
            b[t] = *(const short8*)(wptr + (size_t)(ks * 8 + t) * 512);
#pragma unroll
        for (int t = 0; t < 8; ++t) {
            acc0[t] = __builtin_amdgcn_mfma_f32_16x16x32_bf16(a0, b[t], acc0[t], 0, 0, 0);
            acc1[t] = __builtin_amdgcn_mfma_f32_16x16x32_bf16(a1, b[t], acc1[t], 0, 0, 0);
        }
    }

#pragma unroll
    for (int t = 0; t < 8; ++t) {
        float bv = bias[t * 16 + col];
#pragma unroll
        for (int r = 0; r < 4; ++r) {
            int o0 = mbase + quad * 4 + r;
            int o1 = mbase + 16 + quad * 4 + r;
            if (o0 < N_NODES) out[(size_t)o0 * D + t * 16 + col] = acc0[t][r] + bv;
            if (o1 < N_NODES) out[(size_t)o1 * D + t * 16 + col] = acc1[t][r] + bv;
        }
    }
}

extern "C" void kernel_launch(void* const* d_in, const int* in_sizes, int n_in,
                              void* d_out, int out_size, void* d_ws, size_t ws_size,
                              hipStream_t stream) {
    const float* x = (const float*)d_in[0];
    const int* ei = (const int*)d_in[1];
    const float* W = (const float*)d_in[2];
    const float* b = (const float*)d_in[3];
    float* out = (float*)d_out;
    const int* src = ei;            // edge_index[0,:]
    const int* dst = ei + N_EDGES;  // edge_index[1,:]

    // workspace layout:
    //   feats   [N][384] bf16  38.4 MB (cols 0-127 = x, 128-255 = hop1, 256-383 = hop2)
    //   Wr      frag-ordered W bf16, 6144 chunks x 16 B
    //   off     [N+1] i32 | cursor [N] i32 | bsum/bexcl | csr_src [E] i32
    unsigned short* feats = (unsigned short*)d_ws;
    unsigned short* Wr = feats + (size_t)N_NODES * K3;
    int* off = (int*)(Wr + (size_t)D * K3);
    int* cursor = off + (N_NODES + 1);
    int* bsum = cursor + N_NODES;
    int* bexcl = bsum + 256;
    int* csr_src = bexcl + 256;

    const int NB = (N_NODES + 255) / 256;  // 196

    hipMemsetAsync(cursor, 0, (size_t)N_NODES * sizeof(int), stream);

    setup_kernel<<<5493, 256, 0, stream>>>(x, W, dst, feats, Wr, cursor);

    bsum_kernel<<<NB, 256, 0, stream>>>(cursor, bsum);
    scan_bsum_kernel<<<1, 256, 0, stream>>>(bsum, bexcl, off, NB);
    scan_final_kernel<<<NB, 256, 0, stream>>>(cursor, bexcl, off, cursor);
    fill_kernel<<<(N_EDGES + 255) / 256, 256, 0, stream>>>(src, dst, cursor, csr_src);

    const int ggrid = (N_NODES * 64 + 255) / 256;  // one wave per node
    gather_kernel<<<ggrid, 256, 0, stream>>>(feats, off, csr_src, 0, D);
    gather_kernel<<<ggrid, 256, 0, stream>>>(feats, off, csr_src, D, 2 * D);

    gemm_mfma_kernel<<<(N_NODES + 127) / 128, 256, 0, stream>>>(feats, Wr, b, out);
}